// Round 7
// baseline (272.646 us; speedup 1.0000x reference)
//
#include <hip/hip_runtime.h>

// CRF-RNN mean-field, separable filters, ONE kernel per iteration with
// FIELD-PARALLEL redundant z-gather.
// Grid 24(z) x 24(y) x 16(x), N=9216, C=2, 5 iterations.
//
// Ks (theta=3) = Gz (x) Gy (x) Gx  -- exact separable 1-D convs.
// Kb = S160 * E_i E_j * exp(I3_i*I3_j), Taylor NT=5 (err ~1e-7).
// 12 iter fields: f0,f1 = q (theta=3); f(2+2t+c) = P_t*q_c (theta=160).
// 5 norm fields (tmpN): P_t (theta=160), filtered once by pre.
//
// Lessons: R3 hand-rolled grid barrier = L2 wb/inv disaster; R6 showed
// per-dispatch fixed cost ~2.5-3 us once work is wide. So: minimum
// boundaries (1/iter, forced by the z-gather) + wide grids. Each iter
// kernel block (z, g) z-gathers ALL 12 fields for its slice (442 KB from
// L2/LLC, redundant 6x = 64 MB aggregate ~ 2 us), recomputes the pointwise
// update, xy-filters only its 2 fields {2g, 2g+1}. tmp double-buffered.

#define DD 24
#define HH 24
#define WW 16
#define SLICE 384
#define NPTS 9216
#define NT 5
#define NFI 12
#define NFT 17
#define LOG2E 1.4426950408889634f
#define K3L   (LOG2E / 18.0f)
#define K160L (LOG2E / 51200.0f)

static __device__ __forceinline__ int iabs(int a) { return a < 0 ? -a : a; }

// ---- pre: xy separable conv, ONE field per block. grid (DD, 17) ---------
__global__ __launch_bounds__(SLICE)
void k_pre(const float2* __restrict__ u2, const float* __restrict__ rgb,
           float* __restrict__ tmpA, float* __restrict__ tmpN) {
    __shared__ float gk[32];
    __shared__ float sA[HH][WW + 1];
    __shared__ float sB[HH][WW + 1];
    const int z = blockIdx.x, f = blockIdx.y, t = threadIdx.x;
    const int y = t >> 4, x = t & 15;
    const int i = z * SLICE + t;

    const float kk = (f < 2) ? K3L : K160L;
    if (t < DD) gk[t] = exp2f(-(float)(t * t) * kk);

    float v;
    if (f < 2) {
        float2 q = u2[i];
        v = (f == 0) ? q.x : q.y;
    } else {
        float I3 = rgb[i] * (1.f / 3.f);
        float E = exp2f(-0.5f * LOG2E * I3 * I3);
        int k = (f < NFI) ? ((f - 2) >> 1) : (f - NFI);
        float P = E;
        for (int s = 0; s < k; ++s) P *= I3;
        if (f < NFI) {
            float2 q = u2[i];
            v = P * (((f - 2) & 1) ? q.y : q.x);
        } else {
            v = P;
        }
    }
    sA[y][x] = v;
    __syncthreads();

    float a = 0.f;
#pragma unroll
    for (int xp = 0; xp < WW; ++xp) a = fmaf(gk[iabs(x - xp)], sA[y][xp], a);
    sB[y][x] = a;
    __syncthreads();

    float b = 0.f;
#pragma unroll
    for (int yp = 0; yp < HH; ++yp) b = fmaf(gk[iabs(y - yp)], sB[yp][x], b);
    float* dst = (f < NFI) ? (tmpA + f * NPTS) : (tmpN + (f - NFI) * NPTS);
    dst[i] = b;
}

// ---- shared update math -------------------------------------------------
static __device__ __forceinline__ void mf_update(
        const float acc[12], const float* g3s, const float* Pt,
        float inv_nb, int y, int x, int z,
        const float* sw, const float* bw, const float* compat,
        const float2 uu, float* q0o, float* q1o) {
    const float invf[NT] = {1.f, 1.f, 0.5f, 1.f / 6.f, 1.f / 24.f};
    float sx = 0.f, sy = 0.f, sz = 0.f;
#pragma unroll
    for (int xp = 0; xp < WW; ++xp) sx += g3s[iabs(x - xp)];
#pragma unroll
    for (int yp = 0; yp < HH; ++yp) sy += g3s[iabs(y - yp)];
#pragma unroll
    for (int zp = 0; zp < DD; ++zp) sz += g3s[iabs(z - zp)];
    const float inv_ns = 1.0f / (sx * sy * sz);

    float b0 = 0.f, b1 = 0.f;
#pragma unroll
    for (int k = 0; k < NT; ++k) {
        float w = Pt[k] * invf[k];
        b0 = fmaf(w, acc[2 + 2 * k], b0);
        b1 = fmaf(w, acc[3 + 2 * k], b1);
    }
    b0 *= inv_nb;
    b1 *= inv_nb;
    float s0 = acc[0] * inv_ns;
    float s1 = acc[1] * inv_ns;
    float m0 = s0 * sw[0] + b0 * bw[0];
    float m1 = s1 * sw[1] + b1 * bw[1];
    float p0 = fmaf(compat[0], m0, compat[1] * m1);
    float p1 = fmaf(compat[2], m0, compat[3] * m1);
    *q0o = uu.x - p0;
    *q1o = uu.y - p1;
}

// ---- iteration kernel (it 0..3). grid (DD, 6) x SLICE -------------------
// Block (z, g): z-gather all 12 fields for slice z, update (redundant),
// xy-filter fields {2g, 2g+1} of the new q into tdst.
__global__ __launch_bounds__(SLICE)
void k_iter(const float* __restrict__ tsrc, float* __restrict__ tdst,
            const float* __restrict__ tmpN, const float* __restrict__ rgb,
            const float2* __restrict__ u2,
            const float* __restrict__ sw, const float* __restrict__ bw,
            const float* __restrict__ compat,
            float* __restrict__ normb, int it) {
    __shared__ float g3s[32];
    __shared__ float g160s[32];
    __shared__ float2 cA[HH][WW + 1];
    __shared__ float2 cB[HH][WW + 1];
    const int z = blockIdx.x, g = blockIdx.y, t = threadIdx.x;
    const int y = t >> 4, x = t & 15;
    const int i = z * SLICE + t;

    if (t < DD) {
        g3s[t] = exp2f(-(float)(t * t) * K3L);
        g160s[t] = exp2f(-(float)(t * t) * K160L);
    }
    __syncthreads();

    // z-gather of all 12 fields at this slice's points
    float acc[12];
#pragma unroll
    for (int f = 0; f < 12; ++f) acc[f] = 0.f;
    for (int zp = 0; zp < DD; ++zp) {
        int d = iabs(z - zp);
        float w3 = g3s[d], wb = g160s[d];
        const float* base = tsrc + zp * SLICE + t;
        acc[0] = fmaf(w3, base[0], acc[0]);
        acc[1] = fmaf(w3, base[NPTS], acc[1]);
#pragma unroll
        for (int f = 2; f < 12; ++f)
            acc[f] = fmaf(wb, base[f * NPTS], acc[f]);
    }

    const float I3 = rgb[i] * (1.f / 3.f);
    const float E = exp2f(-0.5f * LOG2E * I3 * I3);
    float Pt[NT];
    Pt[0] = E;
#pragma unroll
    for (int k = 1; k < NT; ++k) Pt[k] = Pt[k - 1] * I3;

    float inv_nb;
    if (it == 0) {
        const float invf[NT] = {1.f, 1.f, 0.5f, 1.f / 6.f, 1.f / 24.f};
        float accN[NT] = {0.f, 0.f, 0.f, 0.f, 0.f};
        for (int zp = 0; zp < DD; ++zp) {
            float wb = g160s[iabs(z - zp)];
            const float* base = tmpN + zp * SLICE + t;
#pragma unroll
            for (int k = 0; k < NT; ++k)
                accN[k] = fmaf(wb, base[k * NPTS], accN[k]);
        }
        float nb = 0.f;
#pragma unroll
        for (int k = 0; k < NT; ++k) nb = fmaf(Pt[k] * invf[k], accN[k], nb);
        if (g == 0) normb[i] = nb;
        inv_nb = 1.0f / nb;
    } else {
        inv_nb = 1.0f / normb[i];
    }

    float q0, q1;
    mf_update(acc, g3s, Pt, inv_nb, y, x, z, sw, bw, compat, u2[i], &q0, &q1);

    // xy-filter this block's 2 fields of the new q
    float2 v;
    const float* gk;
    if (g == 0) { v = make_float2(q0, q1); gk = g3s; }
    else        { float P = Pt[g - 1]; v = make_float2(P * q0, P * q1); gk = g160s; }

    cA[y][x] = v;
    __syncthreads();
    float a0 = 0.f, a1 = 0.f;
#pragma unroll
    for (int xp = 0; xp < WW; ++xp) {
        float w = gk[iabs(x - xp)];
        float2 vv = cA[y][xp];
        a0 = fmaf(w, vv.x, a0);
        a1 = fmaf(w, vv.y, a1);
    }
    cB[y][x] = make_float2(a0, a1);
    __syncthreads();
    float b0 = 0.f, b1 = 0.f;
#pragma unroll
    for (int yp = 0; yp < HH; ++yp) {
        float w = gk[iabs(y - yp)];
        float2 vv = cB[yp][x];
        b0 = fmaf(w, vv.x, b0);
        b1 = fmaf(w, vv.y, b1);
    }
    tdst[(2 * g) * NPTS + i] = b0;
    tdst[(2 * g + 1) * NPTS + i] = b1;
}

// ---- final iteration (it 4): z-gather + update + out. grid 72 x 128 -----
__global__ __launch_bounds__(128)
void k_final(const float* __restrict__ tsrc, const float* __restrict__ rgb,
             const float2* __restrict__ u2,
             const float* __restrict__ sw, const float* __restrict__ bw,
             const float* __restrict__ compat,
             const float* __restrict__ normb, float2* __restrict__ out) {
    __shared__ float g3s[32];
    __shared__ float g160s[32];
    const int t = threadIdx.x;
    const int i = blockIdx.x * 128 + t;
    const int z = i / SLICE;
    const int yx = i - z * SLICE;
    const int y = yx >> 4, x = yx & 15;
    const int col = yx;

    if (t < DD) {
        g3s[t] = exp2f(-(float)(t * t) * K3L);
        g160s[t] = exp2f(-(float)(t * t) * K160L);
    }
    __syncthreads();

    float acc[12];
#pragma unroll
    for (int f = 0; f < 12; ++f) acc[f] = 0.f;
    for (int zp = 0; zp < DD; ++zp) {
        int d = iabs(z - zp);
        float w3 = g3s[d], wb = g160s[d];
        const float* base = tsrc + zp * SLICE + col;
        acc[0] = fmaf(w3, base[0], acc[0]);
        acc[1] = fmaf(w3, base[NPTS], acc[1]);
#pragma unroll
        for (int f = 2; f < 12; ++f)
            acc[f] = fmaf(wb, base[f * NPTS], acc[f]);
    }

    const float I3 = rgb[i] * (1.f / 3.f);
    const float E = exp2f(-0.5f * LOG2E * I3 * I3);
    float Pt[NT];
    Pt[0] = E;
#pragma unroll
    for (int k = 1; k < NT; ++k) Pt[k] = Pt[k - 1] * I3;

    float q0, q1;
    mf_update(acc, g3s, Pt, 1.0f / normb[i], y, x, z, sw, bw, compat,
              u2[i], &q0, &q1);
    out[i] = make_float2(q0, q1);
}

extern "C" void kernel_launch(void* const* d_in, const int* in_sizes, int n_in,
                              void* d_out, int out_size, void* d_ws, size_t ws_size,
                              hipStream_t stream) {
    const float2* u2     = (const float2*)d_in[0];
    const float*  rgb    = (const float*)d_in[1];
    const float*  sw     = (const float*)d_in[2];
    const float*  bw     = (const float*)d_in[3];
    const float*  compat = (const float*)d_in[4];
    float2* out = (float2*)d_out;

    float* ws = (float*)d_ws;
    float* tmpA  = ws;                          // 12*NPTS
    float* tmpB  = ws + NFI * NPTS;             // 12*NPTS
    float* tmpN  = ws + 2 * NFI * NPTS;         // 5*NPTS
    float* normb = ws + (2 * NFI + NT) * NPTS;  // NPTS

    k_pre<<<dim3(DD, NFT), SLICE, 0, stream>>>(u2, rgb, tmpA, tmpN);

    const float* tsrc = tmpA;
    float* tdst = tmpB;
    for (int it = 0; it < 4; ++it) {
        k_iter<<<dim3(DD, 6), SLICE, 0, stream>>>(tsrc, tdst, tmpN, rgb, u2,
                                                  sw, bw, compat, normb, it);
        const float* ns = tdst;
        tdst = (float*)tsrc;
        tsrc = ns;
    }
    k_final<<<NPTS / 128, 128, 0, stream>>>(tsrc, rgb, u2, sw, bw, compat,
                                            normb, out);
}

// Round 8
// 103.806 us; speedup vs baseline: 2.6265x; 2.6265x over previous
//
#include <hip/hip_runtime.h>

// CRF-RNN mean-field, separable filters, field-parallel, 11 dispatches.
// Grid 24(z) x 24(y) x 16(x), N=9216, C=2, 5 iterations.
//
// Ks (theta=3) = Gz (x) Gy (x) Gx  -- exact separable 1-D convs.
// Kb = S160 * E_i E_j * exp(I3_i*I3_j), Taylor NT=5 (err ~1e-7).
// 12 iter fields: f0,f1 = q (theta=3); f(2+2t+c) = P_t*q_c (theta=160).
// 5 norm planes (12..16): P_t (theta=160), filtered once.
//
// Structure per iteration: k_zconv (tmp -> zout, ONE field per block) then
// k_xyupd (zout -> pointwise mean-field update, redundant per f-block ->
// xy-filter field f of new q -> tmp). Final iter: k_zconv + tiny k_final.
//
// Lessons baked in: R3 grid barrier = L2 wb/inv disaster. R6: wide grids
// win; per-dispatch fixed cost ~2.5-4 us. R7: 12-plane z-gather per block
// (288 long-stride loads/thread) is latency-serialized (82 us!) -- never
// gather more than ~24 loads/thread of strided planes; pointwise 12-plane
// reads (one batch of independent loads) are fine.

#define DD 24
#define HH 24
#define WW 16
#define SLICE 384
#define NPTS 9216
#define NT 5
#define NFI 12
#define NFT 17
#define LOG2E 1.4426950408889634f
#define K3L   (LOG2E / 18.0f)
#define K160L (LOG2E / 51200.0f)

static __device__ __forceinline__ int iabs(int a) { return a < 0 ? -a : a; }

// ---- pre: xy separable conv of 17 fields from q=u. grid (DD,17) ---------
__global__ __launch_bounds__(SLICE)
void k_pre(const float2* __restrict__ u2, const float* __restrict__ rgb,
           float* __restrict__ tmp) {
    __shared__ float gk[32];
    __shared__ float sA[HH][WW + 1];
    __shared__ float sB[HH][WW + 1];
    const int z = blockIdx.x, f = blockIdx.y, t = threadIdx.x;
    const int y = t >> 4, x = t & 15;
    const int i = z * SLICE + t;

    const float kk = (f < 2) ? K3L : K160L;
    if (t < DD) gk[t] = exp2f(-(float)(t * t) * kk);

    float v;
    if (f < 2) {
        float2 q = u2[i];
        v = (f == 0) ? q.x : q.y;
    } else {
        float I3 = rgb[i] * (1.f / 3.f);
        float E = exp2f(-0.5f * LOG2E * I3 * I3);
        int k = (f < NFI) ? ((f - 2) >> 1) : (f - NFI);
        float P = E;
        for (int s = 0; s < k; ++s) P *= I3;
        if (f < NFI) {
            float2 q = u2[i];
            v = P * (((f - 2) & 1) ? q.y : q.x);
        } else {
            v = P;
        }
    }
    sA[y][x] = v;
    __syncthreads();

    float a = 0.f;
#pragma unroll
    for (int xp = 0; xp < WW; ++xp) a = fmaf(gk[iabs(x - xp)], sA[y][xp], a);
    sB[y][x] = a;
    __syncthreads();

    float b = 0.f;
#pragma unroll
    for (int yp = 0; yp < HH; ++yp) b = fmaf(gk[iabs(y - yp)], sB[yp][x], b);
    tmp[f * NPTS + i] = b;
}

// ---- z conv, ONE field per block. grid (DD, nf) -------------------------
__global__ __launch_bounds__(SLICE)
void k_zconv(const float* __restrict__ tmp, float* __restrict__ zout) {
    __shared__ float gk[32];
    const int z = blockIdx.x, f = blockIdx.y, t = threadIdx.x;
    const float kk = (f < 2) ? K3L : K160L;
    if (t < DD) gk[t] = exp2f(-(float)(t * t) * kk);
    __syncthreads();

    float acc = 0.f;
    const float* p = tmp + f * NPTS + t;
#pragma unroll 4
    for (int zp = 0; zp < DD; ++zp)
        acc = fmaf(gk[iabs(z - zp)], p[zp * SLICE], acc);
    zout[f * NPTS + z * SLICE + t] = acc;
}

// ---- shared pointwise update math ---------------------------------------
static __device__ __forceinline__ void mf_update(
        const float acc[12], const float* g3s, const float* Pt,
        float inv_nb, int y, int x, int z,
        const float* sw, const float* bw, const float* compat,
        const float2 uu, float* q0o, float* q1o) {
    const float invf[NT] = {1.f, 1.f, 0.5f, 1.f / 6.f, 1.f / 24.f};
    float sx = 0.f, sy = 0.f, sz = 0.f;
#pragma unroll
    for (int xp = 0; xp < WW; ++xp) sx += g3s[iabs(x - xp)];
#pragma unroll
    for (int yp = 0; yp < HH; ++yp) sy += g3s[iabs(y - yp)];
#pragma unroll
    for (int zp = 0; zp < DD; ++zp) sz += g3s[iabs(z - zp)];
    const float inv_ns = 1.0f / (sx * sy * sz);

    float b0 = 0.f, b1 = 0.f;
#pragma unroll
    for (int k = 0; k < NT; ++k) {
        float w = Pt[k] * invf[k];
        b0 = fmaf(w, acc[2 + 2 * k], b0);
        b1 = fmaf(w, acc[3 + 2 * k], b1);
    }
    b0 *= inv_nb;
    b1 *= inv_nb;
    float s0 = acc[0] * inv_ns;
    float s1 = acc[1] * inv_ns;
    float m0 = s0 * sw[0] + b0 * bw[0];
    float m1 = s1 * sw[1] + b1 * bw[1];
    float p0 = fmaf(compat[0], m0, compat[1] * m1);
    float p1 = fmaf(compat[2], m0, compat[3] * m1);
    *q0o = uu.x - p0;
    *q1o = uu.y - p1;
}

// ---- fused update + xy conv. grid (DD, 12) ------------------------------
// Block (z,f): read 12 (17 on it==0) z-convolved planes at slice z (one
// batch of independent loads), recompute the pointwise update (redundant
// across the 12 f-blocks), xy-filter field f of the new q into tmp.
__global__ __launch_bounds__(SLICE)
void k_xyupd(const float* __restrict__ zout, const float* __restrict__ rgb,
             const float2* __restrict__ u2,
             const float* __restrict__ sw, const float* __restrict__ bw,
             const float* __restrict__ compat,
             float* __restrict__ normb, float* __restrict__ tmp, int it) {
    __shared__ float g3s[32];
    __shared__ float gk[32];
    __shared__ float sA[HH][WW + 1];
    __shared__ float sB[HH][WW + 1];
    const int z = blockIdx.x, f = blockIdx.y, t = threadIdx.x;
    const int y = t >> 4, x = t & 15;
    const int i = z * SLICE + t;

    if (t < DD) {
        g3s[t] = exp2f(-(float)(t * t) * K3L);
        gk[t] = exp2f(-(float)(t * t) * ((f < 2) ? K3L : K160L));
    }
    __syncthreads();

    float acc[12];
#pragma unroll
    for (int k = 0; k < 12; ++k) acc[k] = zout[k * NPTS + i];

    const float I3 = rgb[i] * (1.f / 3.f);
    const float E = exp2f(-0.5f * LOG2E * I3 * I3);
    float Pt[NT];
    Pt[0] = E;
#pragma unroll
    for (int k = 1; k < NT; ++k) Pt[k] = Pt[k - 1] * I3;

    float inv_nb;
    if (it == 0) {
        const float invf[NT] = {1.f, 1.f, 0.5f, 1.f / 6.f, 1.f / 24.f};
        float nb = 0.f;
#pragma unroll
        for (int k = 0; k < NT; ++k)
            nb = fmaf(Pt[k] * invf[k], zout[(NFI + k) * NPTS + i], nb);
        if (f == 0) normb[i] = nb;
        inv_nb = 1.0f / nb;
    } else {
        inv_nb = 1.0f / normb[i];
    }

    float q0, q1;
    mf_update(acc, g3s, Pt, inv_nb, y, x, z, sw, bw, compat, u2[i], &q0, &q1);

    float v;
    if (f == 0) v = q0;
    else if (f == 1) v = q1;
    else {
        int k = (f - 2) >> 1;
        v = Pt[k] * (((f - 2) & 1) ? q1 : q0);
    }

    sA[y][x] = v;
    __syncthreads();
    float a = 0.f;
#pragma unroll
    for (int xp = 0; xp < WW; ++xp) a = fmaf(gk[iabs(x - xp)], sA[y][xp], a);
    sB[y][x] = a;
    __syncthreads();
    float b = 0.f;
#pragma unroll
    for (int yp = 0; yp < HH; ++yp) b = fmaf(gk[iabs(y - yp)], sB[yp][x], b);
    tmp[f * NPTS + i] = b;
}

// ---- final pointwise update -> out. grid 36 x 256 -----------------------
__global__ __launch_bounds__(256)
void k_final(const float* __restrict__ zout, const float* __restrict__ rgb,
             const float2* __restrict__ u2,
             const float* __restrict__ sw, const float* __restrict__ bw,
             const float* __restrict__ compat,
             const float* __restrict__ normb, float2* __restrict__ out) {
    __shared__ float g3s[32];
    const int t = threadIdx.x;
    const int i = blockIdx.x * 256 + t;
    if (t < DD) g3s[t] = exp2f(-(float)(t * t) * K3L);
    __syncthreads();

    const int z = i / SLICE;
    const int yx = i - z * SLICE;
    const int y = yx >> 4, x = yx & 15;

    float acc[12];
#pragma unroll
    for (int k = 0; k < 12; ++k) acc[k] = zout[k * NPTS + i];

    const float I3 = rgb[i] * (1.f / 3.f);
    const float E = exp2f(-0.5f * LOG2E * I3 * I3);
    float Pt[NT];
    Pt[0] = E;
#pragma unroll
    for (int k = 1; k < NT; ++k) Pt[k] = Pt[k - 1] * I3;

    float q0, q1;
    mf_update(acc, g3s, Pt, 1.0f / normb[i], y, x, z, sw, bw, compat,
              u2[i], &q0, &q1);
    out[i] = make_float2(q0, q1);
}

extern "C" void kernel_launch(void* const* d_in, const int* in_sizes, int n_in,
                              void* d_out, int out_size, void* d_ws, size_t ws_size,
                              hipStream_t stream) {
    const float2* u2     = (const float2*)d_in[0];
    const float*  rgb    = (const float*)d_in[1];
    const float*  sw     = (const float*)d_in[2];
    const float*  bw     = (const float*)d_in[3];
    const float*  compat = (const float*)d_in[4];
    float2* out = (float2*)d_out;

    float* ws = (float*)d_ws;
    float* tmp   = ws;                     // NFT*NPTS
    float* zout  = ws + NFT * NPTS;        // NFT*NPTS
    float* normb = ws + 2 * NFT * NPTS;    // NPTS

    k_pre<<<dim3(DD, NFT), SLICE, 0, stream>>>(u2, rgb, tmp);

    for (int it = 0; it < 5; ++it) {
        k_zconv<<<dim3(DD, it == 0 ? NFT : NFI), SLICE, 0, stream>>>(tmp, zout);
        if (it < 4)
            k_xyupd<<<dim3(DD, NFI), SLICE, 0, stream>>>(zout, rgb, u2, sw, bw,
                                                         compat, normb, tmp, it);
        else
            k_final<<<NPTS / 256, 256, 0, stream>>>(zout, rgb, u2, sw, bw,
                                                    compat, normb, out);
    }
}

// Round 9
// 97.617 us; speedup vs baseline: 2.7930x; 1.0634x over previous
//
#include <hip/hip_runtime.h>

// CRF-RNN mean-field, separable filters, field-PAIRED planes, 11 dispatches.
// Grid 24(z) x 24(y) x 16(x), N=9216, C=2, 5 iterations.
//
// Ks (theta=3) = Gz (x) Gy (x) Gx  -- exact separable 1-D convs.
// Kb = S160 * E_i E_j * exp(I3_i*I3_j), Taylor NT=5 (err ~1e-7).
// 6 iter PAIRS: pair0 = (q0,q1) theta=3; pair(1+t) = (P_t q0, P_t q1) th=160.
// 3 norm pairs (6..8): (P0,P1),(P2,P3),(P4,0) th=160, filtered once.
//
// Structure/iter: k_zconv (tmp2 -> zout2, one pair per block, no LDS) then
// k_xyupd (zout2 -> pointwise update (redundant per pair-block) -> xy-conv of
// pair p -> tmp2). Final iter: k_zconv + pointwise k_final.
//
// Lessons: R3 grid barrier = L2 wb/inv disaster. R6/R8: wide grids, marginal
// dispatch ~1.4us, per-kernel exec ~4us = instruction overhead -> this round
// strips it: raw v_exp_f32 (__builtin_amdgcn_exp2f), float2 planes, no LDS
// in zconv/final, inv_ns precomputed once (normS), one conv table in xyupd.
// R7: never z-gather >~24 strided plane-loads per thread.

#define DD 24
#define HH 24
#define WW 16
#define SLICE 384
#define NPTS 9216
#define NT 5
#define NPAIR 6
#define NPTOT 9
#define LOG2E 1.4426950408889634f
#define K3L   (LOG2E / 18.0f)
#define K160L (LOG2E / 51200.0f)
#define EXP2  __builtin_amdgcn_exp2f

static __device__ __forceinline__ int iabs(int a) { return a < 0 ? -a : a; }

// ---- pre: xy conv of 9 pairs from q=u. grid (DD, 9) ---------------------
__global__ __launch_bounds__(SLICE)
void k_pre(const float2* __restrict__ u2, const float* __restrict__ rgb,
           float2* __restrict__ tmp2, float* __restrict__ normS) {
    __shared__ float gk[32];
    __shared__ float2 sA[HH][WW + 1];
    __shared__ float2 sB[HH][WW + 1];
    const int z = blockIdx.x, p = blockIdx.y, t = threadIdx.x;
    const int y = t >> 4, x = t & 15;
    const int i = z * SLICE + t;

    const float kk = (p == 0) ? K3L : K160L;
    if (t < DD) gk[t] = EXP2(-(float)(t * t) * kk);

    const float I3 = rgb[i] * (1.f / 3.f);
    float Pt[NT];
    Pt[0] = EXP2(-0.5f * LOG2E * I3 * I3);
#pragma unroll
    for (int k = 1; k < NT; ++k) Pt[k] = Pt[k - 1] * I3;

    float2 v;
    if (p == 0) {
        v = u2[i];
    } else if (p < NPAIR) {
        float2 q = u2[i];
        float P = Pt[p - 1];
        v = make_float2(P * q.x, P * q.y);
    } else {
        int j = p - NPAIR;
        v = make_float2(Pt[2 * j], (j < 2) ? Pt[2 * j + 1] : 0.f);
    }
    sA[y][x] = v;
    __syncthreads();

    float a0 = 0.f, a1 = 0.f;
#pragma unroll
    for (int xp = 0; xp < WW; ++xp) {
        float w = gk[iabs(x - xp)];
        float2 vv = sA[y][xp];
        a0 = fmaf(w, vv.x, a0);
        a1 = fmaf(w, vv.y, a1);
    }
    sB[y][x] = make_float2(a0, a1);
    __syncthreads();
    float b0 = 0.f, b1 = 0.f;
#pragma unroll
    for (int yp = 0; yp < HH; ++yp) {
        float w = gk[iabs(y - yp)];
        float2 vv = sB[yp][x];
        b0 = fmaf(w, vv.x, b0);
        b1 = fmaf(w, vv.y, b1);
    }
    tmp2[p * NPTS + i] = make_float2(b0, b1);

    if (p == 0) {
        // inverse spatial normalization, stored once (gk == g3 here)
        float sx = 0.f, sy = 0.f, sz = 0.f;
#pragma unroll
        for (int xp = 0; xp < WW; ++xp) sx += gk[iabs(x - xp)];
#pragma unroll
        for (int yp = 0; yp < HH; ++yp) sy += gk[iabs(y - yp)];
#pragma unroll
        for (int zp = 0; zp < DD; ++zp) sz += gk[iabs(z - zp)];
        normS[i] = 1.0f / (sx * sy * sz);
    }
}

// ---- z conv, ONE pair per block, no LDS. grid (DD, np) ------------------
__global__ __launch_bounds__(SLICE)
void k_zconv(const float2* __restrict__ tmp2, float2* __restrict__ zout2) {
    const int z = blockIdx.x, p = blockIdx.y, t = threadIdx.x;
    const float kk = (p == 0) ? K3L : K160L;
    float acc0 = 0.f, acc1 = 0.f;
    const float2* src = tmp2 + p * NPTS + t;
#pragma unroll 6
    for (int zp = 0; zp < DD; ++zp) {
        int d = z - zp;
        float w = EXP2(-(float)(d * d) * kk);
        float2 v = src[zp * SLICE];
        acc0 = fmaf(w, v.x, acc0);
        acc1 = fmaf(w, v.y, acc1);
    }
    zout2[p * NPTS + z * SLICE + t] = make_float2(acc0, acc1);
}

// ---- shared pointwise update ------------------------------------------
static __device__ __forceinline__ void mf_update(
        const float2 zp_[NPAIR], const float* Pt, float inv_ns, float inv_nb,
        const float* sw, const float* bw, const float* compat,
        const float2 uu, float* q0o, float* q1o) {
    const float invf[NT] = {1.f, 1.f, 0.5f, 1.f / 6.f, 1.f / 24.f};
    float b0 = 0.f, b1 = 0.f;
#pragma unroll
    for (int k = 0; k < NT; ++k) {
        float w = Pt[k] * invf[k];
        b0 = fmaf(w, zp_[1 + k].x, b0);
        b1 = fmaf(w, zp_[1 + k].y, b1);
    }
    b0 *= inv_nb;
    b1 *= inv_nb;
    float s0 = zp_[0].x * inv_ns;
    float s1 = zp_[0].y * inv_ns;
    float m0 = s0 * sw[0] + b0 * bw[0];
    float m1 = s1 * sw[1] + b1 * bw[1];
    float p0 = fmaf(compat[0], m0, compat[1] * m1);
    float p1 = fmaf(compat[2], m0, compat[3] * m1);
    *q0o = uu.x - p0;
    *q1o = uu.y - p1;
}

// ---- fused update + xy conv of pair p. grid (DD, 6) ---------------------
__global__ __launch_bounds__(SLICE)
void k_xyupd(const float2* __restrict__ zout2, const float* __restrict__ rgb,
             const float2* __restrict__ u2,
             const float* __restrict__ sw, const float* __restrict__ bw,
             const float* __restrict__ compat,
             const float* __restrict__ normS, float* __restrict__ normB,
             float2* __restrict__ tmp2, int it) {
    __shared__ float gk[32];
    __shared__ float2 sA[HH][WW + 1];
    __shared__ float2 sB[HH][WW + 1];
    const int z = blockIdx.x, p = blockIdx.y, t = threadIdx.x;
    const int y = t >> 4, x = t & 15;
    const int i = z * SLICE + t;

    const float kk = (p == 0) ? K3L : K160L;
    if (t < DD) gk[t] = EXP2(-(float)(t * t) * kk);

    float2 zp_[NPAIR];
#pragma unroll
    for (int k = 0; k < NPAIR; ++k) zp_[k] = zout2[k * NPTS + i];

    const float I3 = rgb[i] * (1.f / 3.f);
    float Pt[NT];
    Pt[0] = EXP2(-0.5f * LOG2E * I3 * I3);
#pragma unroll
    for (int k = 1; k < NT; ++k) Pt[k] = Pt[k - 1] * I3;

    float inv_nb;
    if (it == 0) {
        float2 n0 = zout2[6 * NPTS + i];
        float2 n1 = zout2[7 * NPTS + i];
        float2 n2 = zout2[8 * NPTS + i];
        float nb = Pt[0] * n0.x + Pt[1] * n0.y + 0.5f * Pt[2] * n1.x
                 + (1.f / 6.f) * Pt[3] * n1.y + (1.f / 24.f) * Pt[4] * n2.x;
        if (p == 0) normB[i] = nb;
        inv_nb = 1.0f / nb;
    } else {
        inv_nb = 1.0f / normB[i];
    }

    float q0, q1;
    mf_update(zp_, Pt, normS[i], inv_nb, sw, bw, compat, u2[i], &q0, &q1);

    float2 v;
    if (p == 0) v = make_float2(q0, q1);
    else { float P = Pt[p - 1]; v = make_float2(P * q0, P * q1); }

    sA[y][x] = v;
    __syncthreads();
    float a0 = 0.f, a1 = 0.f;
#pragma unroll
    for (int xp = 0; xp < WW; ++xp) {
        float w = gk[iabs(x - xp)];
        float2 vv = sA[y][xp];
        a0 = fmaf(w, vv.x, a0);
        a1 = fmaf(w, vv.y, a1);
    }
    sB[y][x] = make_float2(a0, a1);
    __syncthreads();
    float b0 = 0.f, b1 = 0.f;
#pragma unroll
    for (int yp = 0; yp < HH; ++yp) {
        float w = gk[iabs(y - yp)];
        float2 vv = sB[yp][x];
        b0 = fmaf(w, vv.x, b0);
        b1 = fmaf(w, vv.y, b1);
    }
    tmp2[p * NPTS + i] = make_float2(b0, b1);
}

// ---- final pointwise update -> out. grid 36 x 256, no LDS ---------------
__global__ __launch_bounds__(256)
void k_final(const float2* __restrict__ zout2, const float* __restrict__ rgb,
             const float2* __restrict__ u2,
             const float* __restrict__ sw, const float* __restrict__ bw,
             const float* __restrict__ compat,
             const float* __restrict__ normS, const float* __restrict__ normB,
             float2* __restrict__ out) {
    const int i = blockIdx.x * 256 + threadIdx.x;

    float2 zp_[NPAIR];
#pragma unroll
    for (int k = 0; k < NPAIR; ++k) zp_[k] = zout2[k * NPTS + i];

    const float I3 = rgb[i] * (1.f / 3.f);
    float Pt[NT];
    Pt[0] = EXP2(-0.5f * LOG2E * I3 * I3);
#pragma unroll
    for (int k = 1; k < NT; ++k) Pt[k] = Pt[k - 1] * I3;

    float q0, q1;
    mf_update(zp_, Pt, normS[i], 1.0f / normB[i], sw, bw, compat,
              u2[i], &q0, &q1);
    out[i] = make_float2(q0, q1);
}

extern "C" void kernel_launch(void* const* d_in, const int* in_sizes, int n_in,
                              void* d_out, int out_size, void* d_ws, size_t ws_size,
                              hipStream_t stream) {
    const float2* u2     = (const float2*)d_in[0];
    const float*  rgb    = (const float*)d_in[1];
    const float*  sw     = (const float*)d_in[2];
    const float*  bw     = (const float*)d_in[3];
    const float*  compat = (const float*)d_in[4];
    float2* out = (float2*)d_out;

    float2* ws2   = (float2*)d_ws;
    float2* tmp2  = ws2;                        // NPTOT*NPTS float2
    float2* zout2 = ws2 + NPTOT * NPTS;         // NPTOT*NPTS float2
    float*  normS = (float*)(ws2 + 2 * NPTOT * NPTS);   // NPTS
    float*  normB = normS + NPTS;                        // NPTS

    k_pre<<<dim3(DD, NPTOT), SLICE, 0, stream>>>(u2, rgb, tmp2, normS);

    for (int it = 0; it < 5; ++it) {
        k_zconv<<<dim3(DD, it == 0 ? NPTOT : NPAIR), SLICE, 0, stream>>>(tmp2, zout2);
        if (it < 4)
            k_xyupd<<<dim3(DD, NPAIR), SLICE, 0, stream>>>(zout2, rgb, u2, sw, bw,
                                                           compat, normS, normB,
                                                           tmp2, it);
        else
            k_final<<<NPTS / 256, 256, 0, stream>>>(zout2, rgb, u2, sw, bw,
                                                    compat, normS, normB, out);
    }
}